// Round 2
// baseline (880.608 us; speedup 1.0000x reference)
//
#include <hip/hip_runtime.h>

// DiffeomorphicLearnerTorch: 8-step Euler flow of a Gaussian-RKHS deformation.
// R2: latency-bound fix. B-fragments for both GEMMs are 16B-contiguous in
// global (Zb rows / ATb rows) -> load direct from L2, no sZj/sAj staging.
// LDS = sZi (staged once) + double-buffered sP => ONE barrier per j-tile.
// exp factorization: P = e_i * e_j * exp(2*C1*S); e_j lane-scalar, e_i folded
// into epilogue (before chunk-0 affine accumulate). 64KB LDS + <=128 regs
// => 2 blocks/CU (16 waves) for cross-block latency hiding.

#define N_PTS 4096
#define DIM   256
#define DT_C  0.125f
#define C1    (1.0f/512.0f)   // 1/(2*rho^2), rho=16

typedef __bf16 bf16x8 __attribute__((ext_vector_type(8)));
typedef float  f32x16 __attribute__((ext_vector_type(16)));
typedef float  f32x4v __attribute__((ext_vector_type(4)));
typedef unsigned int   u32x4 __attribute__((ext_vector_type(4)));
typedef unsigned short u16x4 __attribute__((ext_vector_type(4)));
typedef unsigned short u16x8 __attribute__((ext_vector_type(8)));

__device__ __forceinline__ unsigned short f2bf(float f) {
  unsigned int u = __builtin_bit_cast(unsigned int, f);
  u += 0x7fffu + ((u >> 16) & 1u);          // RNE
  return (unsigned short)(u >> 16);
}
__device__ __forceinline__ float bf2f(unsigned short s) {
  unsigned int u = ((unsigned int)s) << 16;
  return __builtin_bit_cast(float, u);
}

// ---------------- transpose+convert A ----------------
__global__ __launch_bounds__(256) void k_transpose(const float* __restrict__ A,
                                                   unsigned short* __restrict__ ATb) {
  __shared__ float sT[64][65];
  const int j0 = blockIdx.x * 64;
  const int d0 = blockIdx.y * 64;
  const int t  = blockIdx.z;
  const int tid = threadIdx.x;
  const float* Ab = A + (size_t)t * N_PTS * DIM;
  unsigned short* Ob = ATb + (size_t)t * DIM * N_PTS;
#pragma unroll
  for (int i = 0; i < 16; ++i) {
    int e = i * 256 + tid;
    int r = e >> 6, c = e & 63;
    sT[r][c] = Ab[(size_t)(j0 + r) * DIM + d0 + c];
  }
  __syncthreads();
#pragma unroll
  for (int i = 0; i < 16; ++i) {
    int e = i * 256 + tid;
    int r = e >> 6, c = e & 63;          // r: local d, c: local j
    Ob[(size_t)(d0 + r) * N_PTS + j0 + c] = f2bf(sT[c][r]);
  }
}

// ---------------- init: Zb, erow=exp(-rowsq/512) from X ----------------
__global__ __launch_bounds__(256) void k_init(const float* __restrict__ X,
                                              unsigned short* __restrict__ Zb,
                                              float* __restrict__ erow) {
  const int b = blockIdx.x, tid = threadIdx.x;
  const int w = tid >> 6, lane = tid & 63;
#pragma unroll
  for (int rr = 0; rr < 4; ++rr) {
    int row = b * 16 + w * 4 + rr;
    size_t base = (size_t)row * DIM + lane * 4;
    f32x4v z = *(const f32x4v*)(X + base);
    u16x4 zb; float s = 0.f;
#pragma unroll
    for (int i = 0; i < 4; ++i) { zb[i] = f2bf(z[i]); s += z[i] * z[i]; }
    *(u16x4*)(Zb + base) = zb;
#pragma unroll
    for (int off = 32; off > 0; off >>= 1) s += __shfl_down(s, off);
    if (lane == 0) erow[row] = __expf(-s * C1);
  }
}

// ---------------- fused flash kernel ----------------
// grid: x = chunk (0..7, 512 j's), y = i-tile (0..63, 64 rows). 512 thr = 8 waves.
// Wave (wr=wid>>2 in {0,1}, wc=wid&3) owns:
//   GEMM1: S[wr*32..+32][wc*32..+32] of the 64x128 S tile (j-tile=128)
//   GEMM2: O[wr*32..+32][wc*64..+64] of the 64x256 O tile
// B-frags for both GEMMs load 16B-contiguous direct from global (L2-resident).
__global__ __launch_bounds__(512, 4) void k_flash(
    const unsigned short* __restrict__ Zb, const float* __restrict__ erow,
    const unsigned short* __restrict__ ATt,   // [256][4096] bf16 for this step
    const float* __restrict__ Aaff_t,         // [256][256] f32 for this step
    unsigned short* __restrict__ Opart) {
  __shared__ unsigned short sZi[64 * 256];      // 32 KiB, rows 512B, swizzled
  __shared__ unsigned short sP[2][64 * 128];    // 2 x 16 KiB, rows 256B, swizzled

  const int tid = threadIdx.x;
  const int lane = tid & 63;
  const int wid = tid >> 6;
  const int l31 = lane & 31;
  const int lhi = lane >> 5;
  const int koff = lhi * 8;
  const int chunk = blockIdx.x;
  const int i0 = blockIdx.y * 64;
  const int jbase = chunk * 512;
  const int wr = wid >> 2, wc = wid & 3;

  // stage Zi tile (64 rows x 256) once, swizzled
#pragma unroll
  for (int p = 0; p < 4; ++p) {
    int lin = p * 512 + tid;
    int row = lin >> 5, blk = lin & 31;
    u32x4 v = *(const u32x4*)(Zb + (size_t)(i0 + row) * DIM + blk * 8);
    int b2 = (blk & 24) | ((blk ^ row) & 7);
    *(u32x4*)((char*)sZi + row * 512 + (b2 << 4)) = v;
  }
  __syncthreads();

  f32x16 O0, O1;
#pragma unroll
  for (int i = 0; i < 16; ++i) { O0[i] = 0.f; O1[i] = 0.f; }

  const int arow = wr * 32 + l31;            // sZi row for A-frags
  const int prb = wr * 32 + 4 * lhi;         // C-layout row base

  // ---- j-loop: 4 tiles of 128 ----
  for (int jt = 0; jt < 4; ++jt) {
    const int jj0 = jbase + jt * 128;
    // GEMM1: S = Zi @ Zj^T (A from LDS, B direct from global)
    f32x16 S;
#pragma unroll
    for (int i = 0; i < 16; ++i) S[i] = 0.f;
    {
      const unsigned short* bptr = Zb + (size_t)(jj0 + wc * 32 + l31) * DIM + koff;
#pragma unroll 4
      for (int ks = 0; ks < 16; ++ks) {
        int blk = ks * 2 + lhi;
        int b2 = (blk & 24) | ((blk ^ arow) & 7);
        bf16x8 af = *(const bf16x8*)((const char*)sZi + arow * 512 + (b2 << 4));
        bf16x8 bf = __builtin_bit_cast(bf16x8, *(const u32x4*)(bptr + ks * 16));
        S = __builtin_amdgcn_mfma_f32_32x32x16_bf16(af, bf, S, 0, 0, 0);
      }
    }
    // P' = e_j * exp(2*C1*S) -> sP[jt&1] (bf16, swizzled)
    {
      const int pcol = wc * 32 + l31;
      const float ej = erow[jj0 + pcol];
      const int blk = pcol >> 3;
      const int bytl = (pcol * 2) & 15;
      char* pb = (char*)sP[jt & 1];
#pragma unroll
      for (int c = 0; c < 16; ++c) {
        int prow = prb + (c & 3) + 8 * (c >> 2);
        float p = ej * __expf(2.f * C1 * S[c]);
        int b2 = (blk & 8) | ((blk ^ prow) & 7);
        *(unsigned short*)(pb + prow * 256 + (b2 << 4) + bytl) = f2bf(p);
      }
    }
    __syncthreads();
    // GEMM2: O += P' @ Aj (A from LDS sP, B direct from global ATt)
    {
      const char* pb = (const char*)sP[jt & 1];
      const unsigned short* bp0 = ATt + (size_t)(wc * 64 + l31) * N_PTS + jj0 + koff;
      const unsigned short* bp1 = bp0 + (size_t)32 * N_PTS;
#pragma unroll 2
      for (int ks = 0; ks < 8; ++ks) {
        int blk = ks * 2 + lhi;
        int b2 = (blk & 8) | ((blk ^ arow) & 7);
        bf16x8 av = *(const bf16x8*)(pb + arow * 256 + (b2 << 4));
        bf16x8 bv0 = __builtin_bit_cast(bf16x8, *(const u32x4*)(bp0 + ks * 16));
        bf16x8 bv1 = __builtin_bit_cast(bf16x8, *(const u32x4*)(bp1 + ks * 16));
        O0 = __builtin_amdgcn_mfma_f32_32x32x16_bf16(av, bv0, O0, 0, 0, 0);
        O1 = __builtin_amdgcn_mfma_f32_32x32x16_bf16(av, bv1, O1, 0, 0, 0);
      }
    }
  }

  // scale by e_i (completes P = e_i*e_j*exp(2*C1*S))
  {
#pragma unroll
    for (int c = 0; c < 16; ++c) {
      float ei = erow[i0 + prb + (c & 3) + 8 * (c >> 2)];
      O0[c] *= ei; O1[c] *= ei;
    }
  }

  // chunk 0 additionally accumulates the affine part: O += Zi @ Aaff_t^T
  if (chunk == 0) {
    const float* ap0 = Aaff_t + (size_t)(wc * 64 + l31) * DIM + koff;
    const float* ap1 = ap0 + (size_t)32 * DIM;
#pragma unroll 2
    for (int ks = 0; ks < 16; ++ks) {
      int blk = ks * 2 + lhi;
      int b2 = (blk & 24) | ((blk ^ arow) & 7);
      bf16x8 af = *(const bf16x8*)((const char*)sZi + arow * 512 + (b2 << 4));
      f32x4v f0 = *(const f32x4v*)(ap0 + ks * 16);
      f32x4v f1 = *(const f32x4v*)(ap0 + ks * 16 + 4);
      f32x4v g0 = *(const f32x4v*)(ap1 + ks * 16);
      f32x4v g1 = *(const f32x4v*)(ap1 + ks * 16 + 4);
      u16x8 t0, t1;
#pragma unroll
      for (int i = 0; i < 4; ++i) {
        t0[i] = f2bf(f0[i]); t0[4 + i] = f2bf(f1[i]);
        t1[i] = f2bf(g0[i]); t1[4 + i] = f2bf(g1[i]);
      }
      O0 = __builtin_amdgcn_mfma_f32_32x32x16_bf16(af, __builtin_bit_cast(bf16x8, t0), O0, 0, 0, 0);
      O1 = __builtin_amdgcn_mfma_f32_32x32x16_bf16(af, __builtin_bit_cast(bf16x8, t1), O1, 0, 0, 0);
    }
  }

  // epilogue -> Opart[chunk] bf16
  {
    unsigned short* ob = Opart + (size_t)chunk * N_PTS * DIM + (size_t)wc * 64 + l31;
#pragma unroll
    for (int c = 0; c < 16; ++c) {
      int row = i0 + prb + (c & 3) + 8 * (c >> 2);
      ob[(size_t)row * DIM]      = f2bf(O0[c]);
      ob[(size_t)row * DIM + 32] = f2bf(O1[c]);
    }
  }
}

// ---------------- update: Z += DT*(sum partials + baff); emit Zb, erow ----------------
__global__ __launch_bounds__(256) void k_update(const float* __restrict__ Zin,
                                                const unsigned short* __restrict__ Opart,
                                                const float* __restrict__ baff_t,
                                                float* __restrict__ Zout,
                                                unsigned short* __restrict__ Zb,
                                                float* __restrict__ erow) {
  const int b = blockIdx.x, tid = threadIdx.x;
  const int w = tid >> 6, lane = tid & 63;
  f32x4v bv = *(const f32x4v*)(baff_t + lane * 4);
#pragma unroll
  for (int rr = 0; rr < 4; ++rr) {
    int row = b * 16 + w * 4 + rr;
    size_t base = (size_t)row * DIM + lane * 4;
    f32x4v z = *(const f32x4v*)(Zin + base);
    f32x4v s = bv;
#pragma unroll
    for (int c = 0; c < 8; ++c) {
      u16x4 p = *(const u16x4*)(Opart + (size_t)c * N_PTS * DIM + base);
#pragma unroll
      for (int i = 0; i < 4; ++i) s[i] += bf2f(p[i]);
    }
    u16x4 zb; float sv = 0.f;
#pragma unroll
    for (int i = 0; i < 4; ++i) {
      z[i] += DT_C * s[i];
      zb[i] = f2bf(z[i]);
      sv += z[i] * z[i];
    }
    *(f32x4v*)(Zout + base) = z;
    *(u16x4*)(Zb + base) = zb;
#pragma unroll
    for (int off = 32; off > 0; off >>= 1) sv += __shfl_down(sv, off);
    if (lane == 0) erow[row] = __expf(-sv * C1);
  }
}

extern "C" void kernel_launch(void* const* d_in, const int* in_sizes, int n_in,
                              void* d_out, int out_size, void* d_ws, size_t ws_size,
                              hipStream_t stream) {
  const float* X    = (const float*)d_in[0];
  const float* A    = (const float*)d_in[1];
  const float* Aaff = (const float*)d_in[2];
  const float* baff = (const float*)d_in[3];
  float* out = (float*)d_out;

  char* w = (char*)d_ws;
  size_t off = 0;
  unsigned short* ATb = (unsigned short*)(w + off); off += (size_t)8 * DIM * N_PTS * 2;  // 16 MiB
  unsigned short* Zb  = (unsigned short*)(w + off); off += (size_t)N_PTS * DIM * 2;      // 2 MiB
  float* erow = (float*)(w + off); off += (size_t)N_PTS * 4;
  float* Zf   = (float*)(w + off); off += (size_t)N_PTS * DIM * 4;                       // 4 MiB
  unsigned short* Opart = (unsigned short*)(w + off); off += (size_t)8 * N_PTS * DIM * 2; // 16 MiB
  (void)ws_size; (void)in_sizes; (void)n_in; (void)out_size;

  k_transpose<<<dim3(64, 4, 8), 256, 0, stream>>>(A, ATb);
  k_init<<<256, 256, 0, stream>>>(X, Zb, erow);

  const float* zin = X;
  for (int t = 0; t < 8; ++t) {
    float* zout = (t == 7) ? out : Zf;   // in-place safe: each thread rmw's its own elems
    k_flash<<<dim3(8, 64), 512, 0, stream>>>(
        Zb, erow, ATb + (size_t)t * DIM * N_PTS, Aaff + (size_t)t * DIM * DIM, Opart);
    k_update<<<256, 256, 0, stream>>>(zin, Opart, baff + (size_t)t * DIM, zout, Zb, erow);
    zin = zout;
  }
}

// Round 4
// 430.283 us; speedup vs baseline: 2.0466x; 2.0466x over previous
//
#include <hip/hip_runtime.h>

// DiffeomorphicLearnerTorch, R4: R3 pipeline + ei-scaling fix.
// Per step: Z += DT*(Z@Aaff^T + b + [ei*ej*exp(2*C1*Z@Z^T)]@A_t)
// ei is folded into the producer's P write (P = ei*ej*exp(2*C1*S)), so the
// consumer accumulator is never post-scaled and the distributed affine
// slices accumulate correctly (R3 bug: affine got multiplied by ei).
// All MFMA B-feeds are frag-linear (1KB coalesced bursts):
//   Zf  [128 jblk][16 ks][64 lane]x16B  bf16 fragments of Z (rebuilt each step)
//   ATf [t][8 ds][256 jb][64 lane]x16B  bf16 fragments of A_t^T (built once)
// k_flash: 256 blocks (8 chunks x 32 i-tiles), 512 thr. Waves 0-3: GEMM1+exp
// (j-tile n); waves 4-7: GEMM2 (j-tile n-1). One barrier per j-tile.
// sAj: 3-buffer ring (stage n+1 / ready n / read n-1); sP: double buffer.

#define N_PTS 4096
#define DIM   256
#define DT_C  0.125f
#define C1    (1.0f/512.0f)

typedef __bf16 bf16x8 __attribute__((ext_vector_type(8)));
typedef float  f32x16 __attribute__((ext_vector_type(16)));
typedef float  f32x4v __attribute__((ext_vector_type(4)));
typedef unsigned int   u32x4 __attribute__((ext_vector_type(4)));
typedef unsigned short u16x8 __attribute__((ext_vector_type(8)));

__device__ __forceinline__ unsigned short f2bf(float f) {
  unsigned int u = __builtin_bit_cast(unsigned int, f);
  u += 0x7fffu + ((u >> 16) & 1u);          // RNE
  return (unsigned short)(u >> 16);
}
__device__ __forceinline__ float bf2f(unsigned short s) {
  unsigned int u = ((unsigned int)s) << 16;
  return __builtin_bit_cast(float, u);
}

// ---- ATf: A[t][4096][256] f32 -> frag-linear bf16 B-operand tiles ----
__global__ __launch_bounds__(256) void k_prep(const float* __restrict__ A,
                                              unsigned short* __restrict__ ATf) {
  __shared__ float sT[64][36];
  const int jgrp = blockIdx.x, ds = blockIdx.y, t = blockIdx.z;
  const int tid = threadIdx.x;
  const float* Ab = A + (size_t)t * N_PTS * DIM;
  {
    const int j_l = tid >> 2, dq = tid & 3;
    const float* src = Ab + (size_t)(jgrp * 64 + j_l) * DIM + ds * 32 + dq * 8;
    f32x4v v0 = *(const f32x4v*)src, v1 = *(const f32x4v*)(src + 4);
    *(f32x4v*)&sT[j_l][dq * 8] = v0;
    *(f32x4v*)&sT[j_l][dq * 8 + 4] = v1;
  }
  __syncthreads();
  const int jb_l = tid >> 6, l = tid & 63, l31 = l & 31, lhi = l >> 5;
  u16x8 o;
#pragma unroll
  for (int e = 0; e < 8; ++e) o[e] = f2bf(sT[jb_l * 16 + lhi * 8 + e][l31]);
  unsigned short* dst = ATf + (size_t)t * (8 * 256 * 64 * 8)
                      + ((size_t)(ds * 256 + jgrp * 4 + jb_l) * 64 + l) * 8;
  *(u16x8*)dst = o;
}

// ---- init: X -> Zf frags + erow ----
__global__ __launch_bounds__(256) void k_init(const float* __restrict__ X,
                                              unsigned short* __restrict__ Zf,
                                              float* __restrict__ erow) {
  const int tid = threadIdx.x;
  const int r = blockIdx.x * 8 + (tid >> 5), o = tid & 31;
  const size_t base = (size_t)r * DIM + o * 8;
  f32x4v z0 = *(const f32x4v*)(X + base), z1 = *(const f32x4v*)(X + base + 4);
  u16x8 zb; float s = 0.f;
#pragma unroll
  for (int i = 0; i < 4; ++i) { zb[i] = f2bf(z0[i]); zb[4 + i] = f2bf(z1[i]);
                                s += z0[i] * z0[i] + z1[i] * z1[i]; }
  *(u16x8*)(Zf + ((size_t)((r >> 5) * 16 + (o >> 1)) * 64 + (o & 1) * 32 + (r & 31)) * 8) = zb;
#pragma unroll
  for (int d = 16; d > 0; d >>= 1) s += __shfl_down(s, d, 32);
  if (o == 0) erow[r] = __expf(-s * C1);
}

// ---- fused flash ----
__global__ __launch_bounds__(512, 2) void k_flash(
    const unsigned short* __restrict__ Zf, const float* __restrict__ erow,
    const unsigned short* __restrict__ ATf_t,  // this step's frag tiles
    const float* __restrict__ Aaff_t,          // [256][256] f32
    unsigned short* __restrict__ Opart) {
  __shared__ unsigned short sAj[3][32 * 512];  // 3 x 32KB, frag-linear slots
  __shared__ unsigned short sP[2][128 * 64];   // 2 x 16KB, row-major swizzled

  const int tid = threadIdx.x, lane = tid & 63, wid = tid >> 6;
  const int l31 = lane & 31, lhi = lane >> 5;
  const int chunk = blockIdx.x;
  const int i0 = blockIdx.y * 128;
  const int jb16 = chunk * 32;

  // stage jtile nt's Aj slots (this wave's 4 of 32) into sAj[nt%3]
#define STAGE(nt)                                                              \
  {                                                                            \
    unsigned short* dstb = sAj[(nt) % 3];                                      \
    _Pragma("unroll")                                                          \
    for (int q = 0; q < 4; ++q) {                                              \
      int s = wid * 4 + q;                                                     \
      int ds_ = s >> 2, ksl = s & 3;                                           \
      const unsigned short* src = ATf_t +                                      \
          ((size_t)(ds_ * 256 + jb16 + (nt) * 4 + ksl) * 64 + lane) * 8;       \
      *(u32x4*)&dstb[s * 512 + lane * 8] = *(const u32x4*)src;                 \
    }                                                                          \
  }

  STAGE(0);
  __syncthreads();

  if (wid < 4) {
    // ================= producer: GEMM1 + exp =================
    const int g1 = wid;
    bf16x8 af[16];
    {
      const unsigned short* ap = Zf + (((size_t)((i0 >> 5) + g1) * 16) * 64 + lane) * 8;
#pragma unroll
      for (int ks = 0; ks < 16; ++ks)
        af[ks] = __builtin_bit_cast(bf16x8, *(const u32x4*)(ap + ks * 512));
    }
    // loop-invariant ei for this wave's 32 S-rows (C-layout order)
    float eI[16];
#pragma unroll
    for (int c = 0; c < 16; ++c)
      eI[c] = erow[i0 + g1 * 32 + 4 * lhi + (c & 3) + 8 * (c >> 2)];

    for (int n = 0; n <= 8; ++n) {
      if (n < 8) {
        if (n < 7) STAGE(n + 1);
        // GEMM1: S(64 j's) = Zi[g1*32..+32] @ Zj^T
        f32x16 S0, S1;
#pragma unroll
        for (int i = 0; i < 16; ++i) { S0[i] = 0.f; S1[i] = 0.f; }
        {
          const unsigned short* bp =
              Zf + (((size_t)(chunk * 16 + n * 2) * 16) * 64 + lane) * 8;
#pragma unroll
          for (int ks = 0; ks < 16; ++ks) {
            bf16x8 b0 = __builtin_bit_cast(bf16x8, *(const u32x4*)(bp + ks * 512));
            bf16x8 b1 = __builtin_bit_cast(bf16x8, *(const u32x4*)(bp + 8192 + ks * 512));
            S0 = __builtin_amdgcn_mfma_f32_32x32x16_bf16(af[ks], b0, S0, 0, 0, 0);
            S1 = __builtin_amdgcn_mfma_f32_32x32x16_bf16(af[ks], b1, S1, 0, 0, 0);
          }
        }
        // P = ei * ej * exp(2*C1*S) -> sP[n&1]   (full kernel value K[i][j])
        const int jj0 = chunk * 512 + n * 64;
        const float ej0 = erow[jj0 + l31];
        const float ej1 = erow[jj0 + 32 + l31];
        unsigned short* pb = sP[n & 1];
        const int blk0 = l31 >> 3, cl = l31 & 7;
#pragma unroll
        for (int c = 0; c < 16; ++c) {
          const int row = g1 * 32 + 4 * lhi + (c & 3) + 8 * (c >> 2);
          pb[row * 64 + ((blk0 ^ (row & 7)) * 8) + cl] =
              f2bf(eI[c] * ej0 * __expf(2.f * C1 * S0[c]));
          pb[row * 64 + (((4 + blk0) ^ (row & 7)) * 8) + cl] =
              f2bf(eI[c] * ej1 * __expf(2.f * C1 * S1[c]));
        }
      }
      __syncthreads();
    }
  } else {
    // ================= consumer: GEMM2 (+ affine slice) =================
    const int w4 = wid - 4;
    f32x16 Oa[4][2];
#pragma unroll
    for (int rs = 0; rs < 4; ++rs)
#pragma unroll
      for (int ct = 0; ct < 2; ++ct)
#pragma unroll
        for (int i = 0; i < 16; ++i) Oa[rs][ct][i] = 0.f;

    for (int n = 0; n <= 8; ++n) {
      if (n < 7) STAGE(n + 1);
      if (n == 0) {
        // affine slice: this chunk covers ks_g = chunk*2 + {0,1} of K=256
        // (accumulates UNSCALED into Oa — valid since Oa is never post-scaled)
#pragma unroll
        for (int q = 0; q < 2; ++q) {
          const int ksg = chunk * 2 + q;
          bf16x8 a[4];
#pragma unroll
          for (int rs = 0; rs < 4; ++rs)
            a[rs] = __builtin_bit_cast(bf16x8, *(const u32x4*)(
                Zf + (((size_t)((i0 >> 5) + rs) * 16 + ksg) * 64 + lane) * 8));
#pragma unroll
          for (int ct = 0; ct < 2; ++ct) {
            const int d = w4 * 64 + ct * 32 + l31;
            const float* bp = Aaff_t + (size_t)d * DIM + ksg * 16 + lhi * 8;
            f32x4v f0 = *(const f32x4v*)bp, f1 = *(const f32x4v*)(bp + 4);
            u16x8 tb;
#pragma unroll
            for (int i = 0; i < 4; ++i) { tb[i] = f2bf(f0[i]); tb[4 + i] = f2bf(f1[i]); }
            bf16x8 bv = __builtin_bit_cast(bf16x8, tb);
#pragma unroll
            for (int rs = 0; rs < 4; ++rs)
              Oa[rs][ct] = __builtin_amdgcn_mfma_f32_32x32x16_bf16(a[rs], bv, Oa[rs][ct], 0, 0, 0);
          }
        }
      }
      if (n >= 1) {
        const int m = n - 1;
        const unsigned short* aj = sAj[m % 3];
        const unsigned short* pb = sP[m & 1];
#pragma unroll
        for (int ks = 0; ks < 4; ++ks) {
          bf16x8 a[4], b[2];
          const int blk = ks * 2 + lhi;
#pragma unroll
          for (int rs = 0; rs < 4; ++rs) {
            const int row = rs * 32 + l31;
            a[rs] = *(const bf16x8*)&pb[row * 64 + ((blk ^ (row & 7)) * 8)];
          }
#pragma unroll
          for (int ct = 0; ct < 2; ++ct)
            b[ct] = *(const bf16x8*)&aj[((w4 * 2 + ct) * 4 + ks) * 512 + lane * 8];
#pragma unroll
          for (int rs = 0; rs < 4; ++rs)
#pragma unroll
            for (int ct = 0; ct < 2; ++ct)
              Oa[rs][ct] = __builtin_amdgcn_mfma_f32_32x32x16_bf16(a[rs], b[ct], Oa[rs][ct], 0, 0, 0);
        }
      }
      __syncthreads();
    }
    // epilogue: write Opart[chunk] (no scaling — P already carries ei*ej)
    unsigned short* ob = Opart + (size_t)chunk * N_PTS * DIM + (size_t)w4 * 64 + l31;
#pragma unroll
    for (int rs = 0; rs < 4; ++rs)
#pragma unroll
      for (int cg = 0; cg < 4; ++cg) {
        const int rbase = rs * 32 + 4 * lhi + 8 * cg;
#pragma unroll
        for (int e = 0; e < 4; ++e) {
          const int c = cg * 4 + e;
          const size_t ro = (size_t)(i0 + rbase + e) * DIM;
          ob[ro]      = f2bf(Oa[rs][0][c]);
          ob[ro + 32] = f2bf(Oa[rs][1][c]);
        }
      }
  }
#undef STAGE
}

// ---- update: Z += DT*(sum partials + baff); emit Zf frags + erow ----
__global__ __launch_bounds__(256) void k_update(const float* __restrict__ Zin,
                                                const unsigned short* __restrict__ Opart,
                                                const float* __restrict__ baff_t,
                                                float* __restrict__ Zout,
                                                unsigned short* __restrict__ Zf,
                                                float* __restrict__ erow) {
  const int tid = threadIdx.x;
  const int r = blockIdx.x * 8 + (tid >> 5), o = tid & 31;
  const size_t base = (size_t)r * DIM + o * 8;
  f32x4v z0 = *(const f32x4v*)(Zin + base), z1 = *(const f32x4v*)(Zin + base + 4);
  f32x4v s0 = *(const f32x4v*)(baff_t + o * 8), s1 = *(const f32x4v*)(baff_t + o * 8 + 4);
#pragma unroll
  for (int c = 0; c < 8; ++c) {
    u16x8 p = *(const u16x8*)(Opart + (size_t)c * N_PTS * DIM + base);
#pragma unroll
    for (int i = 0; i < 4; ++i) { s0[i] += bf2f(p[i]); s1[i] += bf2f(p[4 + i]); }
  }
  u16x8 zb; float sv = 0.f;
#pragma unroll
  for (int i = 0; i < 4; ++i) {
    z0[i] += DT_C * s0[i]; z1[i] += DT_C * s1[i];
    zb[i] = f2bf(z0[i]); zb[4 + i] = f2bf(z1[i]);
    sv += z0[i] * z0[i] + z1[i] * z1[i];
  }
  *(f32x4v*)(Zout + base) = z0;
  *(f32x4v*)(Zout + base + 4) = z1;
  *(u16x8*)(Zf + ((size_t)((r >> 5) * 16 + (o >> 1)) * 64 + (o & 1) * 32 + (r & 31)) * 8) = zb;
#pragma unroll
  for (int d = 16; d > 0; d >>= 1) sv += __shfl_down(sv, d, 32);
  if (o == 0) erow[r] = __expf(-sv * C1);
}

extern "C" void kernel_launch(void* const* d_in, const int* in_sizes, int n_in,
                              void* d_out, int out_size, void* d_ws, size_t ws_size,
                              hipStream_t stream) {
  const float* X    = (const float*)d_in[0];
  const float* A    = (const float*)d_in[1];
  const float* Aaff = (const float*)d_in[2];
  const float* baff = (const float*)d_in[3];
  float* out = (float*)d_out;

  char* w = (char*)d_ws;
  size_t off = 0;
  unsigned short* ATf = (unsigned short*)(w + off); off += (size_t)8 * 8 * 256 * 64 * 8 * 2; // 16 MiB
  unsigned short* Zf  = (unsigned short*)(w + off); off += (size_t)N_PTS * DIM * 2;          // 2 MiB
  float* erow = (float*)(w + off); off += (size_t)N_PTS * 4;
  float* Zf32 = (float*)(w + off); off += (size_t)N_PTS * DIM * 4;                           // 4 MiB
  unsigned short* Opart = (unsigned short*)(w + off); off += (size_t)8 * N_PTS * DIM * 2;    // 16 MiB
  (void)ws_size; (void)in_sizes; (void)n_in; (void)out_size;

  k_prep<<<dim3(64, 8, 8), 256, 0, stream>>>(A, ATf);
  k_init<<<512, 256, 0, stream>>>(X, Zf, erow);

  const float* zin = X;
  for (int t = 0; t < 8; ++t) {
    float* zout = (t == 7) ? out : Zf32;  // in-place safe after t=0
    k_flash<<<dim3(8, 32), 512, 0, stream>>>(
        Zf, erow, ATf + (size_t)t * (8 * 256 * 64 * 8), Aaff + (size_t)t * DIM * DIM, Opart);
    k_update<<<512, 256, 0, stream>>>(zin, Opart, baff + (size_t)t * DIM, zout, Zf, erow);
    zin = zout;
  }
}

// Round 5
// 391.341 us; speedup vs baseline: 2.2502x; 1.0995x over previous
//
#include <hip/hip_runtime.h>

// DiffeomorphicLearnerTorch, R5.
// Per step: Z += DT*(Z@Aaff^T + b + [ei*ej*exp(2*C1*Z@Z^T)]@A_t)
// Key changes vs R4 (which ran ~45us/dispatch at 1 block/CU):
//  - NO sAj LDS staging: each ATf fragment is consumed by exactly one wave,
//    so consumers load B direct from global (frag-linear 1KB bursts, L2-hot).
//  - LDS = sP double buffer only (16KB) -> 2 blocks/CU.
//  - i-tile 64: producer S=16 regs, consumer O=64 regs; all waves <=128 VGPR
//    (__launch_bounds__(512,4)) -> 4 waves/SIMD for latency hiding.
// Frag-linear layouts (verified in R4):
//   Zf  [128 jblk][16 ks][64 lane]x8 bf16   (A- and B-operand fragments of Z)
//   ATf [t][8 dblk][256 jb][64 lane]x8 bf16 (B-operand fragments of A_t^T)

#define N_PTS 4096
#define DIM   256
#define DT_C  0.125f
#define C1    (1.0f/512.0f)

typedef __bf16 bf16x8 __attribute__((ext_vector_type(8)));
typedef float  f32x16 __attribute__((ext_vector_type(16)));
typedef float  f32x4v __attribute__((ext_vector_type(4)));
typedef unsigned int   u32x4 __attribute__((ext_vector_type(4)));
typedef unsigned short u16x8 __attribute__((ext_vector_type(8)));

__device__ __forceinline__ unsigned short f2bf(float f) {
  unsigned int u = __builtin_bit_cast(unsigned int, f);
  u += 0x7fffu + ((u >> 16) & 1u);          // RNE
  return (unsigned short)(u >> 16);
}
__device__ __forceinline__ float bf2f(unsigned short s) {
  unsigned int u = ((unsigned int)s) << 16;
  return __builtin_bit_cast(float, u);
}

// ---- ATf: A[t][4096][256] f32 -> frag-linear bf16 B-operand tiles ----
__global__ __launch_bounds__(256) void k_prep(const float* __restrict__ A,
                                              unsigned short* __restrict__ ATf) {
  __shared__ float sT[64][36];
  const int jgrp = blockIdx.x, ds = blockIdx.y, t = blockIdx.z;
  const int tid = threadIdx.x;
  const float* Ab = A + (size_t)t * N_PTS * DIM;
  {
    const int j_l = tid >> 2, dq = tid & 3;
    const float* src = Ab + (size_t)(jgrp * 64 + j_l) * DIM + ds * 32 + dq * 8;
    f32x4v v0 = *(const f32x4v*)src, v1 = *(const f32x4v*)(src + 4);
    *(f32x4v*)&sT[j_l][dq * 8] = v0;
    *(f32x4v*)&sT[j_l][dq * 8 + 4] = v1;
  }
  __syncthreads();
  const int jb_l = tid >> 6, l = tid & 63, l31 = l & 31, lhi = l >> 5;
  u16x8 o;
#pragma unroll
  for (int e = 0; e < 8; ++e) o[e] = f2bf(sT[jb_l * 16 + lhi * 8 + e][l31]);
  unsigned short* dst = ATf + (size_t)t * (8 * 256 * 64 * 8)
                      + ((size_t)(ds * 256 + jgrp * 4 + jb_l) * 64 + l) * 8;
  *(u16x8*)dst = o;
}

// ---- init: X -> Zf frags + erow ----
__global__ __launch_bounds__(256) void k_init(const float* __restrict__ X,
                                              unsigned short* __restrict__ Zf,
                                              float* __restrict__ erow) {
  const int tid = threadIdx.x;
  const int r = blockIdx.x * 8 + (tid >> 5), o = tid & 31;
  const size_t base = (size_t)r * DIM + o * 8;
  f32x4v z0 = *(const f32x4v*)(X + base), z1 = *(const f32x4v*)(X + base + 4);
  u16x8 zb; float s = 0.f;
#pragma unroll
  for (int i = 0; i < 4; ++i) { zb[i] = f2bf(z0[i]); zb[4 + i] = f2bf(z1[i]);
                                s += z0[i] * z0[i] + z1[i] * z1[i]; }
  *(u16x8*)(Zf + ((size_t)((r >> 5) * 16 + (o >> 1)) * 64 + (o & 1) * 32 + (r & 31)) * 8) = zb;
#pragma unroll
  for (int d = 16; d > 0; d >>= 1) s += __shfl_down(s, d, 32);
  if (o == 0) erow[r] = __expf(-s * C1);
}

// ---- fused flash ----
// grid (8 chunks, 64 i-tiles of 64 rows), 512 thr = 8 waves, 2 blocks/CU.
// waves 0-3: producer (ip=wid>>1, jh=wid&1): S = Zi(32) @ Zj(32)^T, K=256;
//            P = ei*ej*exp(2*C1*S) -> sP[n&1].
// waves 4-7: consumer cd=wid-4: O(64i x 64d) += P @ A_t  (B direct global);
//            + affine slice ksg=chunk*2+{0,1} at n==0.
__global__ __launch_bounds__(512, 4) void k_flash(
    const unsigned short* __restrict__ Zf, const float* __restrict__ erow,
    const unsigned short* __restrict__ ATf_t,
    const float* __restrict__ Aaff_t,
    unsigned short* __restrict__ Opart) {
  __shared__ unsigned short sP[2][64 * 64];   // 2 x 8KB, swizzled rows of 128B

  const int tid = threadIdx.x, lane = tid & 63, wid = tid >> 6;
  const int l31 = lane & 31, lhi = lane >> 5;
  const int chunk = blockIdx.x;
  const int i0 = blockIdx.y * 64;
  const int ib = i0 >> 5;

  if (wid < 4) {
    // ================= producer =================
    const int ip = wid >> 1, jh = wid & 1;
    bf16x8 af[16];
    {
      const unsigned short* ap = Zf + ((size_t)(ib + ip) * 16 * 64 + lane) * 8;
#pragma unroll
      for (int ks = 0; ks < 16; ++ks)
        af[ks] = __builtin_bit_cast(bf16x8, *(const u32x4*)(ap + ks * 512));
    }
    float eI[16];
#pragma unroll
    for (int c = 0; c < 16; ++c)
      eI[c] = erow[i0 + ip * 32 + 4 * lhi + (c & 3) + 8 * (c >> 2)];

    for (int n = 0; n < 8; ++n) {
      f32x16 S;
#pragma unroll
      for (int i = 0; i < 16; ++i) S[i] = 0.f;
      {
        const int jblk = chunk * 16 + n * 2 + jh;
        const unsigned short* bp = Zf + ((size_t)jblk * 16 * 64 + lane) * 8;
#pragma unroll
        for (int ks = 0; ks < 16; ++ks) {
          bf16x8 b = __builtin_bit_cast(bf16x8, *(const u32x4*)(bp + ks * 512));
          S = __builtin_amdgcn_mfma_f32_32x32x16_bf16(af[ks], b, S, 0, 0, 0);
        }
      }
      const float ej = erow[chunk * 512 + n * 64 + jh * 32 + l31];
      unsigned short* pb = sP[n & 1];
      const int blk = jh * 4 + (l31 >> 3), cl = l31 & 7;
#pragma unroll
      for (int c = 0; c < 16; ++c) {
        const int row = ip * 32 + 4 * lhi + (c & 3) + 8 * (c >> 2);
        pb[row * 64 + ((blk ^ (row & 7)) * 8) + cl] =
            f2bf(eI[c] * ej * __expf(2.f * C1 * S[c]));
      }
      __syncthreads();
    }
    __syncthreads();   // match consumer's 9th barrier
  } else {
    // ================= consumer =================
    const int cd = wid - 4;   // d-sub 0..3 (64 d's each), owns all 64 i rows
    f32x16 O[2][2];
#pragma unroll
    for (int rs = 0; rs < 2; ++rs)
#pragma unroll
      for (int ct = 0; ct < 2; ++ct)
#pragma unroll
        for (int i = 0; i < 16; ++i) O[rs][ct][i] = 0.f;

    // affine slice (unscaled): ksg = chunk*2 + {0,1} of K=256
#pragma unroll
    for (int q = 0; q < 2; ++q) {
      const int ksg = chunk * 2 + q;
      bf16x8 a[2];
#pragma unroll
      for (int rs = 0; rs < 2; ++rs)
        a[rs] = __builtin_bit_cast(bf16x8, *(const u32x4*)(
            Zf + (((size_t)(ib + rs) * 16 + ksg) * 64 + lane) * 8));
#pragma unroll
      for (int ct = 0; ct < 2; ++ct) {
        const int d = cd * 64 + ct * 32 + l31;
        const float* bp = Aaff_t + (size_t)d * DIM + ksg * 16 + lhi * 8;
        f32x4v f0 = *(const f32x4v*)bp, f1 = *(const f32x4v*)(bp + 4);
        u16x8 tb;
#pragma unroll
        for (int i = 0; i < 4; ++i) { tb[i] = f2bf(f0[i]); tb[4 + i] = f2bf(f1[i]); }
        bf16x8 bv = __builtin_bit_cast(bf16x8, tb);
#pragma unroll
        for (int rs = 0; rs < 2; ++rs)
          O[rs][ct] = __builtin_amdgcn_mfma_f32_32x32x16_bf16(a[rs], bv, O[rs][ct], 0, 0, 0);
      }
    }
    __syncthreads();   // barrier 1 (producer finished tile 0)

    for (int n = 1; n <= 8; ++n) {
      const int m = n - 1;
      const unsigned short* pb = sP[m & 1];
#pragma unroll
      for (int ks = 0; ks < 4; ++ks) {
        bf16x8 a[2], b[2];
        const int blk = ks * 2 + lhi;
#pragma unroll
        for (int rs = 0; rs < 2; ++rs) {
          const int row = rs * 32 + l31;
          a[rs] = *(const bf16x8*)&pb[row * 64 + ((blk ^ (row & 7)) * 8)];
        }
#pragma unroll
        for (int ct = 0; ct < 2; ++ct)
          b[ct] = __builtin_bit_cast(bf16x8, *(const u32x4*)(ATf_t +
              ((size_t)((cd * 2 + ct) * 256 + chunk * 32 + m * 4 + ks) * 64 + lane) * 8));
#pragma unroll
        for (int rs = 0; rs < 2; ++rs)
#pragma unroll
          for (int ct = 0; ct < 2; ++ct)
            O[rs][ct] = __builtin_amdgcn_mfma_f32_32x32x16_bf16(a[rs], b[ct], O[rs][ct], 0, 0, 0);
      }
      __syncthreads();
    }

    // epilogue -> Opart[chunk] bf16 (P already carries ei*ej; no scaling)
    unsigned short* ob = Opart + (size_t)chunk * N_PTS * DIM + (size_t)cd * 64 + l31;
#pragma unroll
    for (int rs = 0; rs < 2; ++rs)
#pragma unroll
      for (int c = 0; c < 16; ++c) {
        const int row = i0 + rs * 32 + 4 * lhi + (c & 3) + 8 * (c >> 2);
        ob[(size_t)row * DIM]      = f2bf(O[rs][0][c]);
        ob[(size_t)row * DIM + 32] = f2bf(O[rs][1][c]);
      }
  }
}

// ---- update: Z += DT*(sum partials + baff); emit Zf frags + erow ----
__global__ __launch_bounds__(256) void k_update(const float* __restrict__ Zin,
                                                const unsigned short* __restrict__ Opart,
                                                const float* __restrict__ baff_t,
                                                float* __restrict__ Zout,
                                                unsigned short* __restrict__ Zf,
                                                float* __restrict__ erow) {
  const int tid = threadIdx.x;
  const int r = blockIdx.x * 8 + (tid >> 5), o = tid & 31;
  const size_t base = (size_t)r * DIM + o * 8;
  f32x4v z0 = *(const f32x4v*)(Zin + base), z1 = *(const f32x4v*)(Zin + base + 4);
  f32x4v s0 = *(const f32x4v*)(baff_t + o * 8), s1 = *(const f32x4v*)(baff_t + o * 8 + 4);
#pragma unroll
  for (int c = 0; c < 8; ++c) {
    u16x8 p = *(const u16x8*)(Opart + (size_t)c * N_PTS * DIM + base);
#pragma unroll
    for (int i = 0; i < 4; ++i) { s0[i] += bf2f(p[i]); s1[i] += bf2f(p[4 + i]); }
  }
  u16x8 zb; float sv = 0.f;
#pragma unroll
  for (int i = 0; i < 4; ++i) {
    z0[i] += DT_C * s0[i]; z1[i] += DT_C * s1[i];
    zb[i] = f2bf(z0[i]); zb[4 + i] = f2bf(z1[i]);
    sv += z0[i] * z0[i] + z1[i] * z1[i];
  }
  *(f32x4v*)(Zout + base) = z0;
  *(f32x4v*)(Zout + base + 4) = z1;
  *(u16x8*)(Zf + ((size_t)((r >> 5) * 16 + (o >> 1)) * 64 + (o & 1) * 32 + (r & 31)) * 8) = zb;
#pragma unroll
  for (int d = 16; d > 0; d >>= 1) sv += __shfl_down(sv, d, 32);
  if (o == 0) erow[r] = __expf(-sv * C1);
}

extern "C" void kernel_launch(void* const* d_in, const int* in_sizes, int n_in,
                              void* d_out, int out_size, void* d_ws, size_t ws_size,
                              hipStream_t stream) {
  const float* X    = (const float*)d_in[0];
  const float* A    = (const float*)d_in[1];
  const float* Aaff = (const float*)d_in[2];
  const float* baff = (const float*)d_in[3];
  float* out = (float*)d_out;

  char* w = (char*)d_ws;
  size_t off = 0;
  unsigned short* ATf = (unsigned short*)(w + off); off += (size_t)8 * 8 * 256 * 64 * 8 * 2; // 16 MiB
  unsigned short* Zf  = (unsigned short*)(w + off); off += (size_t)N_PTS * DIM * 2;          // 2 MiB
  float* erow = (float*)(w + off); off += (size_t)N_PTS * 4;
  float* Zf32 = (float*)(w + off); off += (size_t)N_PTS * DIM * 4;                           // 4 MiB
  unsigned short* Opart = (unsigned short*)(w + off); off += (size_t)8 * N_PTS * DIM * 2;    // 16 MiB
  (void)ws_size; (void)in_sizes; (void)n_in; (void)out_size;

  k_prep<<<dim3(64, 8, 8), 256, 0, stream>>>(A, ATf);
  k_init<<<512, 256, 0, stream>>>(X, Zf, erow);

  const float* zin = X;
  for (int t = 0; t < 8; ++t) {
    float* zout = (t == 7) ? out : Zf32;  // in-place safe after t=0
    k_flash<<<dim3(8, 64), 512, 0, stream>>>(
        Zf, erow, ATf + (size_t)t * (8 * 256 * 64 * 8), Aaff + (size_t)t * DIM * DIM, Opart);
    k_update<<<512, 256, 0, stream>>>(zin, Opart, baff + (size_t)t * DIM, zout, Zf, erow);
    zin = zout;
  }
}

// Round 6
// 380.979 us; speedup vs baseline: 2.3114x; 1.0272x over previous
//
#include <hip/hip_runtime.h>

// DiffeomorphicLearnerTorch, R6.
// Per step: Z += DT*(Z@Aaff^T + b + [ei*ej*exp(2*C1*Z@Z^T)]@A_t)
// R5 ran k_flash ~40us (same as R4 despite 2x occupancy) => exposed-latency,
// theory: 128-VGPR cap + af[16] resident (64 regs) serializes b-frag loads
// into ~2-deep batches with full L2 latency between.
// R6 fix: (a) producer A-operand moved to LDS (sZi, frag-linear 32KB staged
// once -> ds_read_b128 per MFMA), freeing 64 VGPRs; (b) explicit hoist of
// all 16 producer / 8 consumer global b-frag loads into register arrays
// (MLP 16/8). LDS 48KB/block keeps 2 blocks/CU.
// Frag-linear layouts (verified R4/R5):
//   Zf  [128 jblk][16 ks][64 lane]x8 bf16
//   ATf [t][8 dblk][256 jb][64 lane]x8 bf16

#define N_PTS 4096
#define DIM   256
#define DT_C  0.125f
#define C1    (1.0f/512.0f)

typedef __bf16 bf16x8 __attribute__((ext_vector_type(8)));
typedef float  f32x16 __attribute__((ext_vector_type(16)));
typedef float  f32x4v __attribute__((ext_vector_type(4)));
typedef unsigned int   u32x4 __attribute__((ext_vector_type(4)));
typedef unsigned short u16x8 __attribute__((ext_vector_type(8)));

__device__ __forceinline__ unsigned short f2bf(float f) {
  unsigned int u = __builtin_bit_cast(unsigned int, f);
  u += 0x7fffu + ((u >> 16) & 1u);          // RNE
  return (unsigned short)(u >> 16);
}
__device__ __forceinline__ float bf2f(unsigned short s) {
  unsigned int u = ((unsigned int)s) << 16;
  return __builtin_bit_cast(float, u);
}

// ---- ATf: A[t][4096][256] f32 -> frag-linear bf16 B-operand tiles ----
__global__ __launch_bounds__(256) void k_prep(const float* __restrict__ A,
                                              unsigned short* __restrict__ ATf) {
  __shared__ float sT[64][36];
  const int jgrp = blockIdx.x, ds = blockIdx.y, t = blockIdx.z;
  const int tid = threadIdx.x;
  const float* Ab = A + (size_t)t * N_PTS * DIM;
  {
    const int j_l = tid >> 2, dq = tid & 3;
    const float* src = Ab + (size_t)(jgrp * 64 + j_l) * DIM + ds * 32 + dq * 8;
    f32x4v v0 = *(const f32x4v*)src, v1 = *(const f32x4v*)(src + 4);
    *(f32x4v*)&sT[j_l][dq * 8] = v0;
    *(f32x4v*)&sT[j_l][dq * 8 + 4] = v1;
  }
  __syncthreads();
  const int jb_l = tid >> 6, l = tid & 63, l31 = l & 31, lhi = l >> 5;
  u16x8 o;
#pragma unroll
  for (int e = 0; e < 8; ++e) o[e] = f2bf(sT[jb_l * 16 + lhi * 8 + e][l31]);
  unsigned short* dst = ATf + (size_t)t * (8 * 256 * 64 * 8)
                      + ((size_t)(ds * 256 + jgrp * 4 + jb_l) * 64 + l) * 8;
  *(u16x8*)dst = o;
}

// ---- init: X -> Zf frags + erow ----
__global__ __launch_bounds__(256) void k_init(const float* __restrict__ X,
                                              unsigned short* __restrict__ Zf,
                                              float* __restrict__ erow) {
  const int tid = threadIdx.x;
  const int r = blockIdx.x * 8 + (tid >> 5), o = tid & 31;
  const size_t base = (size_t)r * DIM + o * 8;
  f32x4v z0 = *(const f32x4v*)(X + base), z1 = *(const f32x4v*)(X + base + 4);
  u16x8 zb; float s = 0.f;
#pragma unroll
  for (int i = 0; i < 4; ++i) { zb[i] = f2bf(z0[i]); zb[4 + i] = f2bf(z1[i]);
                                s += z0[i] * z0[i] + z1[i] * z1[i]; }
  *(u16x8*)(Zf + ((size_t)((r >> 5) * 16 + (o >> 1)) * 64 + (o & 1) * 32 + (r & 31)) * 8) = zb;
#pragma unroll
  for (int d = 16; d > 0; d >>= 1) s += __shfl_down(s, d, 32);
  if (o == 0) erow[r] = __expf(-s * C1);
}

// ---- fused flash ----
// grid (8 chunks, 64 i-tiles of 64 rows), 512 thr = 8 waves, 2 blocks/CU.
// waves 0-3 producer (ip=wid>>1, jh=wid&1): S = Zi(32) @ Zj(32)^T;
//   af from sZi (LDS), b-frags hoisted x16 from global. P -> sP[n&1].
// waves 4-7 consumer cd: O(64i x 64d) += P @ A_t; b hoisted x8 from global;
//   + affine slice ksg=chunk*2+{0,1} (a-frags from sZi).
__global__ __launch_bounds__(512, 4) void k_flash(
    const unsigned short* __restrict__ Zf, const float* __restrict__ erow,
    const unsigned short* __restrict__ ATf_t,
    const float* __restrict__ Aaff_t,
    unsigned short* __restrict__ Opart) {
  __shared__ __align__(16) unsigned short sZi[64 * 256];   // 32KB frag-linear
  __shared__ __align__(16) unsigned short sP[2][64 * 64];  // 2 x 8KB swizzled

  const int tid = threadIdx.x, lane = tid & 63, wid = tid >> 6;
  const int l31 = lane & 31, lhi = lane >> 5;
  const int chunk = blockIdx.x;
  const int i0 = blockIdx.y * 64;
  const int ib = i0 >> 5;

  // stage sZi: 32KB contiguous slice of Zf (frag-linear already)
  {
    const unsigned short* src = Zf + (size_t)ib * 8192;
#pragma unroll
    for (int p = 0; p < 4; ++p)
      *(u32x4*)(sZi + (size_t)(p * 512 + tid) * 8) =
          *(const u32x4*)(src + (size_t)(p * 512 + tid) * 8);
  }
  __syncthreads();

  if (wid < 4) {
    // ================= producer =================
    const int ip = wid >> 1, jh = wid & 1;
    float eI[16];
#pragma unroll
    for (int c = 0; c < 16; ++c)
      eI[c] = erow[i0 + ip * 32 + 4 * lhi + (c & 3) + 8 * (c >> 2)];

    for (int n = 0; n < 8; ++n) {
      // hoist all 16 b-frags (MLP=16)
      u32x4 bv[16];
      {
        const unsigned short* bp =
            Zf + ((size_t)(chunk * 16 + n * 2 + jh) * 16 * 64 + lane) * 8;
#pragma unroll
        for (int ks = 0; ks < 16; ++ks) bv[ks] = *(const u32x4*)(bp + ks * 512);
      }
      f32x16 S;
#pragma unroll
      for (int i = 0; i < 16; ++i) S[i] = 0.f;
#pragma unroll
      for (int ks = 0; ks < 16; ++ks) {
        bf16x8 af = *(const bf16x8*)(sZi + ((size_t)(ip * 16 + ks) * 64 + lane) * 8);
        S = __builtin_amdgcn_mfma_f32_32x32x16_bf16(af, __builtin_bit_cast(bf16x8, bv[ks]), S, 0, 0, 0);
      }
      const float ej = erow[chunk * 512 + n * 64 + jh * 32 + l31];
      unsigned short* pb = sP[n & 1];
      const int blk = jh * 4 + (l31 >> 3), cl = l31 & 7;
#pragma unroll
      for (int c = 0; c < 16; ++c) {
        const int row = ip * 32 + 4 * lhi + (c & 3) + 8 * (c >> 2);
        pb[row * 64 + ((blk ^ (row & 7)) * 8) + cl] =
            f2bf(eI[c] * ej * __expf(2.f * C1 * S[c]));
      }
      __syncthreads();
    }
    __syncthreads();   // match consumer's 9th barrier
  } else {
    // ================= consumer =================
    const int cd = wid - 4;
    f32x16 O[2][2];
#pragma unroll
    for (int rs = 0; rs < 2; ++rs)
#pragma unroll
      for (int ct = 0; ct < 2; ++ct)
#pragma unroll
        for (int i = 0; i < 16; ++i) O[rs][ct][i] = 0.f;

    // affine slice (unscaled): ksg = chunk*2 + {0,1}; a-frags from sZi
#pragma unroll
    for (int q = 0; q < 2; ++q) {
      const int ksg = chunk * 2 + q;
      bf16x8 a[2];
#pragma unroll
      for (int rs = 0; rs < 2; ++rs)
        a[rs] = *(const bf16x8*)(sZi + ((size_t)(rs * 16 + ksg) * 64 + lane) * 8);
#pragma unroll
      for (int ct = 0; ct < 2; ++ct) {
        const int d = cd * 64 + ct * 32 + l31;
        const float* bp = Aaff_t + (size_t)d * DIM + ksg * 16 + lhi * 8;
        f32x4v f0 = *(const f32x4v*)bp, f1 = *(const f32x4v*)(bp + 4);
        u16x8 tb;
#pragma unroll
        for (int i = 0; i < 4; ++i) { tb[i] = f2bf(f0[i]); tb[4 + i] = f2bf(f1[i]); }
        bf16x8 bv = __builtin_bit_cast(bf16x8, tb);
#pragma unroll
        for (int rs = 0; rs < 2; ++rs)
          O[rs][ct] = __builtin_amdgcn_mfma_f32_32x32x16_bf16(a[rs], bv, O[rs][ct], 0, 0, 0);
      }
    }
    __syncthreads();   // barrier 1 (producer finished tile 0)

    for (int n = 1; n <= 8; ++n) {
      const int m = n - 1;
      // hoist the 8 ATf b-frags (MLP=8)
      u32x4 bw[8];
#pragma unroll
      for (int ks = 0; ks < 4; ++ks)
#pragma unroll
        for (int ct = 0; ct < 2; ++ct)
          bw[ks * 2 + ct] = *(const u32x4*)(ATf_t +
              ((size_t)((cd * 2 + ct) * 256 + chunk * 32 + m * 4 + ks) * 64 + lane) * 8);
      const unsigned short* pb = sP[m & 1];
#pragma unroll
      for (int ks = 0; ks < 4; ++ks) {
        bf16x8 a[2];
        const int blk = ks * 2 + lhi;
#pragma unroll
        for (int rs = 0; rs < 2; ++rs) {
          const int row = rs * 32 + l31;
          a[rs] = *(const bf16x8*)&pb[row * 64 + ((blk ^ (row & 7)) * 8)];
        }
#pragma unroll
        for (int rs = 0; rs < 2; ++rs)
#pragma unroll
          for (int ct = 0; ct < 2; ++ct)
            O[rs][ct] = __builtin_amdgcn_mfma_f32_32x32x16_bf16(
                a[rs], __builtin_bit_cast(bf16x8, bw[ks * 2 + ct]), O[rs][ct], 0, 0, 0);
      }
      __syncthreads();
    }

    // epilogue -> Opart[chunk] bf16 (P already carries ei*ej)
    unsigned short* ob = Opart + (size_t)chunk * N_PTS * DIM + (size_t)cd * 64 + l31;
#pragma unroll
    for (int rs = 0; rs < 2; ++rs)
#pragma unroll
      for (int c = 0; c < 16; ++c) {
        const int row = i0 + rs * 32 + 4 * lhi + (c & 3) + 8 * (c >> 2);
        ob[(size_t)row * DIM]      = f2bf(O[rs][0][c]);
        ob[(size_t)row * DIM + 32] = f2bf(O[rs][1][c]);
      }
  }
}

// ---- update: Z += DT*(sum partials + baff); emit Zf frags + erow ----
__global__ __launch_bounds__(256) void k_update(const float* __restrict__ Zin,
                                                const unsigned short* __restrict__ Opart,
                                                const float* __restrict__ baff_t,
                                                float* __restrict__ Zout,
                                                unsigned short* __restrict__ Zf,
                                                float* __restrict__ erow) {
  const int tid = threadIdx.x;
  const int r = blockIdx.x * 8 + (tid >> 5), o = tid & 31;
  const size_t base = (size_t)r * DIM + o * 8;
  f32x4v z0 = *(const f32x4v*)(Zin + base), z1 = *(const f32x4v*)(Zin + base + 4);
  f32x4v s0 = *(const f32x4v*)(baff_t + o * 8), s1 = *(const f32x4v*)(baff_t + o * 8 + 4);
#pragma unroll
  for (int c = 0; c < 8; ++c) {
    u16x8 p = *(const u16x8*)(Opart + (size_t)c * N_PTS * DIM + base);
#pragma unroll
    for (int i = 0; i < 4; ++i) { s0[i] += bf2f(p[i]); s1[i] += bf2f(p[4 + i]); }
  }
  u16x8 zb; float sv = 0.f;
#pragma unroll
  for (int i = 0; i < 4; ++i) {
    z0[i] += DT_C * s0[i]; z1[i] += DT_C * s1[i];
    zb[i] = f2bf(z0[i]); zb[4 + i] = f2bf(z1[i]);
    sv += z0[i] * z0[i] + z1[i] * z1[i];
  }
  *(f32x4v*)(Zout + base) = z0;
  *(f32x4v*)(Zout + base + 4) = z1;
  *(u16x8*)(Zf + ((size_t)((r >> 5) * 16 + (o >> 1)) * 64 + (o & 1) * 32 + (r & 31)) * 8) = zb;
#pragma unroll
  for (int d = 16; d > 0; d >>= 1) sv += __shfl_down(sv, d, 32);
  if (o == 0) erow[r] = __expf(-sv * C1);
}

extern "C" void kernel_launch(void* const* d_in, const int* in_sizes, int n_in,
                              void* d_out, int out_size, void* d_ws, size_t ws_size,
                              hipStream_t stream) {
  const float* X    = (const float*)d_in[0];
  const float* A    = (const float*)d_in[1];
  const float* Aaff = (const float*)d_in[2];
  const float* baff = (const float*)d_in[3];
  float* out = (float*)d_out;

  char* w = (char*)d_ws;
  size_t off = 0;
  unsigned short* ATf = (unsigned short*)(w + off); off += (size_t)8 * 8 * 256 * 64 * 8 * 2; // 16 MiB
  unsigned short* Zf  = (unsigned short*)(w + off); off += (size_t)N_PTS * DIM * 2;          // 2 MiB
  float* erow = (float*)(w + off); off += (size_t)N_PTS * 4;
  float* Zf32 = (float*)(w + off); off += (size_t)N_PTS * DIM * 4;                           // 4 MiB
  unsigned short* Opart = (unsigned short*)(w + off); off += (size_t)8 * N_PTS * DIM * 2;    // 16 MiB
  (void)ws_size; (void)in_sizes; (void)n_in; (void)out_size;

  k_prep<<<dim3(64, 8, 8), 256, 0, stream>>>(A, ATf);
  k_init<<<512, 256, 0, stream>>>(X, Zf, erow);

  const float* zin = X;
  for (int t = 0; t < 8; ++t) {
    float* zout = (t == 7) ? out : Zf32;  // in-place safe after t=0
    k_flash<<<dim3(8, 64), 512, 0, stream>>>(
        Zf, erow, ATf + (size_t)t * (8 * 256 * 64 * 8), Aaff + (size_t)t * DIM * DIM, Opart);
    k_update<<<512, 256, 0, stream>>>(zin, Opart, baff + (size_t)t * DIM, zout, Zf, erow);
    zin = zout;
  }
}